// Round 8
// baseline (6667.408 us; speedup 1.0000x reference)
//
#include <hip/hip_runtime.h>
#include <stdint.h>

#define T_STEPS 2048
#define BATCH   16
#define DIM     1024
#define BD      (BATCH * DIM)
#define SLOTS   4096   // 16 batches * 256 slots, per parity

typedef float    f32x4 __attribute__((ext_vector_type(4)));
typedef unsigned u32x4 __attribute__((ext_vector_type(4)));
typedef __bf16   bf16x8 __attribute__((ext_vector_type(8)));

__device__ __forceinline__ unsigned bf16b(float f) {
  __bf16 b = (__bf16)f; unsigned short s; __builtin_memcpy(&s, &b, 2);
  return (unsigned)s;
}

// ---------------------------------------------------------------------------
// ws: [0,128KB) hX4 = u32x4[2][BATCH][256]; slot j = {tag, bf16 r4j|r4j+1,
// bf16 r4j+2|r4j+3, tag}. Tag at both ends detects torn 16B delivery.
// ---------------------------------------------------------------------------
__global__ void prep_kernel(const float* __restrict__ h0,
                            float* __restrict__ hout,
                            u32x4* __restrict__ hX4) {
  int i = blockIdx.x * blockDim.x + threadIdx.x;
  if (i < BD) hout[i] = h0[i];
  if (i < SLOTS) {
    int b = i >> 8, j = i & 255;
    const float* hp = h0 + b * DIM + 4 * j;
    u32x4 v;
    v.x = 0u; v.w = 0u;                               // tag 0
    v.y = bf16b(hp[0]) | (bf16b(hp[1]) << 16);
    v.z = bf16b(hp[2]) | (bf16b(hp[3]) << 16);
    hX4[i] = v;
    u32x4 inv; inv.x = 0xFFFFFFFFu; inv.w = 0xFFFFFFFFu; inv.y = 0u; inv.z = 0u;
    hX4[SLOTS + i] = inv;                             // parity 1 invalid
  }
}

// ---------------------------------------------------------------------------
// xp = x @ W_x^T + b  (R1-proven)
// ---------------------------------------------------------------------------
__global__ __launch_bounds__(256)
void xp_gemm(const float* __restrict__ X, const float* __restrict__ W,
             const float* __restrict__ Bv, float* __restrict__ XP) {
  __shared__ __bf16 As[128 * 64];
  __shared__ __bf16 Bs[128 * 64];
  const int tid = threadIdx.x;
  const int bm = blockIdx.x & 255;
  const int bn = blockIdx.x >> 8;
  const int w = tid >> 6, l = tid & 63;
  const int wr = w >> 1, wc = w & 1;
  const int sr = tid >> 1, sh = tid & 1;

  const float* xrow = X + (size_t)(bm * 128 + sr) * DIM + sh * 32;
  const float* wrow = W + (size_t)(bn * 128 + sr) * DIM + sh * 32;
  char* AsB = (char*)As;
  char* BsB = (char*)Bs;
  const int swr  = sr * 128;
  const int swzs = (sr & 7) << 4;

  f32x4 acc[4][4];
  const f32x4 z4 = {0.f, 0.f, 0.f, 0.f};
#pragma unroll
  for (int i = 0; i < 4; ++i)
#pragma unroll
    for (int j = 0; j < 4; ++j) acc[i][j] = z4;

  for (int kt = 0; kt < 16; ++kt) {
#pragma unroll
    for (int j = 0; j < 8; ++j) {
      f32x4 a  = *(const f32x4*)(xrow + kt * 64 + 4 * j);
      f32x4 bv = *(const f32x4*)(wrow + kt * 64 + 4 * j);
      union { __bf16 h[4]; unsigned long long u; } pa, pb;
#pragma unroll
      for (int qq = 0; qq < 4; ++qq) { pa.h[qq] = (__bf16)a[qq]; pb.h[qq] = (__bf16)bv[qq]; }
      int c2  = (sh * 32 + 4 * j) * 2;
      int off = swr + (c2 ^ swzs);
      *(unsigned long long*)(AsB + off) = pa.u;
      *(unsigned long long*)(BsB + off) = pb.u;
    }
    __syncthreads();
#pragma unroll
    for (int ks = 0; ks < 2; ++ks) {
      bf16x8 afr[4], bfr[4];
#pragma unroll
      for (int mi = 0; mi < 4; ++mi) {
        int row = wr * 64 + mi * 16 + (l & 15);
        int c2  = ks * 64 + (l >> 4) * 16;
        afr[mi] = *(const bf16x8*)(AsB + row * 128 + (c2 ^ ((row & 7) << 4)));
      }
#pragma unroll
      for (int ni = 0; ni < 4; ++ni) {
        int row = wc * 64 + ni * 16 + (l & 15);
        int c2  = ks * 64 + (l >> 4) * 16;
        bfr[ni] = *(const bf16x8*)(BsB + row * 128 + (c2 ^ ((row & 7) << 4)));
      }
#pragma unroll
      for (int mi = 0; mi < 4; ++mi)
#pragma unroll
        for (int ni = 0; ni < 4; ++ni)
          acc[mi][ni] = __builtin_amdgcn_mfma_f32_16x16x32_bf16(
              afr[mi], bfr[ni], acc[mi][ni], 0, 0, 0);
    }
    __syncthreads();
  }
  const int colb = bn * 128 + wc * 64 + (l & 15);
#pragma unroll
  for (int ni = 0; ni < 4; ++ni) {
    int col = colb + ni * 16;
    float bb = Bv[col];
#pragma unroll
    for (int mi = 0; mi < 4; ++mi) {
      int row = bm * 128 + wr * 64 + mi * 16 + ((l >> 4) << 2);
#pragma unroll
      for (int r = 0; r < 4; ++r)
        XP[(size_t)(row + r) * DIM + col] = acc[mi][ni][r] + bb;
    }
  }
}

// ---------------------------------------------------------------------------
// recurrence. waves_per_eu(4,4) pins 1 WG/CU & a 128-VGPR budget so the
// 64-reg W slice stays register-resident (the R1-R7 floor was L2 W-refetch).
// Exchange: 16B packed tagged slots; wave 0 narrowing-polls 4x1KB quads.
// ---------------------------------------------------------------------------
__global__ __attribute__((amdgpu_flat_work_group_size(1024, 1024)))
__attribute__((amdgpu_waves_per_eu(4, 4)))
void rnn_kernel(const float* __restrict__ Wh, const float* __restrict__ Z,
                const float* __restrict__ gz, const float* __restrict__ gh,
                const float* __restrict__ bg,
                float* __restrict__ out,    // holds xp, overwritten with out
                float* __restrict__ hout,   // [T+1][B][D]
                u32x4* __restrict__ hX4) {
  __shared__ float hb[2][1024];
  const int tid = threadIdx.x;
  const int w   = tid >> 6;
  const int l   = tid & 63;
  const int b   = blockIdx.x >> 4;
  const int s   = blockIdx.x & 15;
  const int r0  = s * 64;
  const int myrow  = r0 + w * 4 + (l & 3);
  const bool writer = (l < 4);

  // W_h slice -> registers: wave w rows r0+4w..+3, lane l K-range [16l,16l+16)
  f32x4 W4[4][4];
  {
    const f32x4* WhV = (const f32x4*)Wh;
#pragma unroll
    for (int r4 = 0; r4 < 4; ++r4) {
      size_t base = (size_t)(r0 + w * 4 + r4) * (DIM / 4) + l * 4;
#pragma unroll
      for (int jj = 0; jj < 4; ++jj) W4[r4][jj] = WhV[base + jj];
    }
  }

  float cgz = 0.f, cgh = 0.f, cbg = 0.f;
  float xpA = 0.f, zA = 0.f, xpB = 0.f, zB = 0.f;
  if (writer) {
    cgz = gz[myrow]; cgh = gh[myrow]; cbg = bg[myrow];
    xpA = out[(size_t)b * DIM + myrow];   // xp[0,b,myrow]
    zA  = Z[(size_t)b * DIM + myrow];
  }

#define TAGOK(Q) __all((int)((Q.x == tt) & (Q.w == tt)))
#define SCAT(K, Q, P) { int qi = 64 * K + l; int wi = ((qi ^ (qi >> 3)) & 255) << 2; \
    f32x4 v; v.x = __uint_as_float(Q.y << 16);                                       \
    v.y = __uint_as_float(Q.y & 0xFFFF0000u);                                        \
    v.z = __uint_as_float(Q.z << 16);                                                \
    v.w = __uint_as_float(Q.z & 0xFFFF0000u);                                        \
    *(f32x4*)&hb[P][wi] = v; }

#define STEP(P, XPC, ZC, XPN, ZN)                                                  \
  {                                                                                \
    const unsigned tt = (unsigned)t;                                               \
    const u32x4* srcq = hX4 + (size_t)(P) * SLOTS + (size_t)b * 256;               \
    u32x4*       dstq = hX4 + (size_t)(P ^ 1) * SLOTS + (size_t)b * 256;           \
    if (w == 0) {                                                                  \
      const char* ap = (const char*)srcq + (l << 4);                               \
      u32x4 q0, q1, q2, q3;                                                        \
      unsigned pend = 0xFu; int rounds = 0;                                        \
      do {                                                                         \
        if (pend & 1u) asm volatile("global_load_dwordx4 %0, %1, off sc1"          \
                                    : "=v"(q0) : "v"(ap) : "memory");              \
        if (pend & 2u) asm volatile("global_load_dwordx4 %0, %1, off offset:1024 sc1" \
                                    : "=v"(q1) : "v"(ap) : "memory");              \
        if (pend & 4u) asm volatile("global_load_dwordx4 %0, %1, off offset:2048 sc1" \
                                    : "=v"(q2) : "v"(ap) : "memory");              \
        if (pend & 8u) asm volatile("global_load_dwordx4 %0, %1, off offset:3072 sc1" \
                                    : "=v"(q3) : "v"(ap) : "memory");              \
        asm volatile("s_waitcnt vmcnt(0)" ::: "memory");                           \
        if ((pend & 1u) && TAGOK(q0)) { SCAT(0, q0, P); pend &= ~1u; }             \
        if ((pend & 2u) && TAGOK(q1)) { SCAT(1, q1, P); pend &= ~2u; }             \
        if ((pend & 4u) && TAGOK(q2)) { SCAT(2, q2, P); pend &= ~4u; }             \
        if ((pend & 8u) && TAGOK(q3)) { SCAT(3, q3, P); pend &= ~8u; }             \
      } while (pend && ++rounds < (1 << 22));                                      \
    }                                                                              \
    /* prefetch t+1 EARLY: ~1000cy before the next poll's vmcnt(0) drain */        \
    if (writer && t + 1 < T_STEPS) {                                               \
      XPN = out[((size_t)(t + 1) * BATCH + b) * DIM + myrow];                      \
      ZN  = Z[((size_t)(t + 1) * BATCH + b) * DIM + myrow];                        \
    }                                                                              \
    __syncthreads();                                                               \
    float acc0 = 0.f, acc1 = 0.f, acc2 = 0.f, acc3 = 0.f;                          \
    _Pragma("unroll")                                                              \
    for (int jj = 0; jj < 4; ++jj) {                                               \
      int qr = 4 * l + jj;                                                         \
      int wb = ((qr ^ (qr >> 3)) & 255) << 2;                                      \
      f32x4 h4 = *(const f32x4*)&hb[P][wb];                                        \
      _Pragma("unroll")                                                            \
      for (int i = 0; i < 4; ++i) {                                                \
        acc0 = fmaf(W4[0][jj][i], h4[i], acc0);                                    \
        acc1 = fmaf(W4[1][jj][i], h4[i], acc1);                                    \
        acc2 = fmaf(W4[2][jj][i], h4[i], acc2);                                    \
        acc3 = fmaf(W4[3][jj][i], h4[i], acc3);                                    \
      }                                                                            \
    }                                                                              \
    float w01 = (l & 1) ? acc0 : acc1;                                             \
    float v01 = ((l & 1) ? acc1 : acc0) + __shfl_xor(w01, 1);                      \
    float w23 = (l & 1) ? acc2 : acc3;                                             \
    float v23 = ((l & 1) ? acc3 : acc2) + __shfl_xor(w23, 1);                      \
    float wv  = (l & 2) ? v01 : v23;                                               \
    float vv  = ((l & 2) ? v23 : v01) + __shfl_xor(wv, 2);                         \
    vv += __shfl_xor(vv, 4);                                                       \
    vv += __shfl_xor(vv, 8);                                                       \
    vv += __shfl_xor(vv, 16);                                                      \
    vv += __shfl_xor(vv, 32);                                                      \
    if (writer) {                                                                  \
      float pre = vv + XPC;                                                        \
      float e2 = __expf(2.0f * pre);                                               \
      float hn = 1.0f - 2.0f / (e2 + 1.0f);                                        \
      float h1 = __shfl(hn, 1), h2 = __shfl(hn, 2), h3 = __shfl(hn, 3);            \
      if (l == 0) {                                                                \
        u32x4 pk;                                                                  \
        pk.x = tt + 1u; pk.w = tt + 1u;                                            \
        pk.y = bf16b(hn) | (bf16b(h1) << 16);                                      \
        pk.z = bf16b(h2) | (bf16b(h3) << 16);                                      \
        u32x4* pp = dstq + (s * 16 + w);                                           \
        asm volatile("global_store_dwordx4 %0, %1, off sc1"                        \
                     :: "v"(pp), "v"(pk) : "memory");                              \
      }                                                                            \
      hout[((size_t)(t + 1) * BATCH + b) * DIM + myrow] = hn;                      \
      float y   = ZC * cgz + hn * cgh + cbg;                                       \
      float sig = 1.0f / (1.0f + __expf(-y));                                      \
      out[((size_t)t * BATCH + b) * DIM + myrow] = hn * (y * sig);                 \
    }                                                                              \
  }

  for (int t = 0; t < T_STEPS; ) {
    STEP(0, xpA, zA, xpB, zB)
    ++t;
    STEP(1, xpB, zB, xpA, zA)
    ++t;
  }
#undef STEP
#undef SCAT
#undef TAGOK
}

extern "C" void kernel_launch(void* const* d_in, const int* in_sizes, int n_in,
                              void* d_out, int out_size, void* d_ws, size_t ws_size,
                              hipStream_t stream) {
  const float* x    = (const float*)d_in[0];
  const float* z    = (const float*)d_in[1];
  const float* h0   = (const float*)d_in[2];
  const float* Wx   = (const float*)d_in[3];
  const float* Wh   = (const float*)d_in[4];
  const float* bias = (const float*)d_in[5];
  const float* gz   = (const float*)d_in[6];
  const float* gh   = (const float*)d_in[7];
  const float* bg   = (const float*)d_in[8];

  float* out  = (float*)d_out;
  float* hout = out + (size_t)T_STEPS * BATCH * DIM;
  u32x4* hX4  = (u32x4*)d_ws;                        // 2*4096*16B = 128 KB

  prep_kernel<<<dim3(64), dim3(256), 0, stream>>>(h0, hout, hX4);
  xp_gemm<<<dim3(2048), dim3(256), 0, stream>>>(x, Wx, bias, out);
  rnn_kernel<<<dim3(256), dim3(1024), 0, stream>>>(Wh, z, gz, gh, bg, out, hout, hX4);
}

// Round 9
// 6656.837 us; speedup vs baseline: 1.0016x; 1.0016x over previous
//
#include <hip/hip_runtime.h>
#include <stdint.h>

#define T_STEPS 2048
#define BATCH   16
#define DIM     1024
#define BD      (BATCH * DIM)
#define SLOTS   4096   // 16 batches * 256 slots, per parity

typedef float    f32x4 __attribute__((ext_vector_type(4)));
typedef unsigned u32x4 __attribute__((ext_vector_type(4)));
typedef __bf16   bf16x8 __attribute__((ext_vector_type(8)));

__device__ __forceinline__ unsigned bf16b(float f) {
  __bf16 b = (__bf16)f; unsigned short s; __builtin_memcpy(&s, &b, 2);
  return (unsigned)s;
}

// ---------------------------------------------------------------------------
// ws: [0,128KB) hX4 = u32x4[2][BATCH][256]; slot j = {tag, bf16 r4j|r4j+1,
// bf16 r4j+2|r4j+3, tag}. Tag at both ends detects torn 16B delivery.
// ---------------------------------------------------------------------------
__global__ void prep_kernel(const float* __restrict__ h0,
                            float* __restrict__ hout,
                            u32x4* __restrict__ hX4) {
  int i = blockIdx.x * blockDim.x + threadIdx.x;
  if (i < BD) hout[i] = h0[i];
  if (i < SLOTS) {
    int b = i >> 8, j = i & 255;
    const float* hp = h0 + b * DIM + 4 * j;
    u32x4 v;
    v.x = 0u; v.w = 0u;                               // tag 0
    v.y = bf16b(hp[0]) | (bf16b(hp[1]) << 16);
    v.z = bf16b(hp[2]) | (bf16b(hp[3]) << 16);
    hX4[i] = v;
    u32x4 inv; inv.x = 0xFFFFFFFFu; inv.w = 0xFFFFFFFFu; inv.y = 0u; inv.z = 0u;
    hX4[SLOTS + i] = inv;                             // parity 1 invalid
  }
}

// ---------------------------------------------------------------------------
// xp = x @ W_x^T + b  (R1-proven)
// ---------------------------------------------------------------------------
__global__ __launch_bounds__(256)
void xp_gemm(const float* __restrict__ X, const float* __restrict__ W,
             const float* __restrict__ Bv, float* __restrict__ XP) {
  __shared__ __bf16 As[128 * 64];
  __shared__ __bf16 Bs[128 * 64];
  const int tid = threadIdx.x;
  const int bm = blockIdx.x & 255;
  const int bn = blockIdx.x >> 8;
  const int w = tid >> 6, l = tid & 63;
  const int wr = w >> 1, wc = w & 1;
  const int sr = tid >> 1, sh = tid & 1;

  const float* xrow = X + (size_t)(bm * 128 + sr) * DIM + sh * 32;
  const float* wrow = W + (size_t)(bn * 128 + sr) * DIM + sh * 32;
  char* AsB = (char*)As;
  char* BsB = (char*)Bs;
  const int swr  = sr * 128;
  const int swzs = (sr & 7) << 4;

  f32x4 acc[4][4];
  const f32x4 z4 = {0.f, 0.f, 0.f, 0.f};
#pragma unroll
  for (int i = 0; i < 4; ++i)
#pragma unroll
    for (int j = 0; j < 4; ++j) acc[i][j] = z4;

  for (int kt = 0; kt < 16; ++kt) {
#pragma unroll
    for (int j = 0; j < 8; ++j) {
      f32x4 a  = *(const f32x4*)(xrow + kt * 64 + 4 * j);
      f32x4 bv = *(const f32x4*)(wrow + kt * 64 + 4 * j);
      union { __bf16 h[4]; unsigned long long u; } pa, pb;
#pragma unroll
      for (int qq = 0; qq < 4; ++qq) { pa.h[qq] = (__bf16)a[qq]; pb.h[qq] = (__bf16)bv[qq]; }
      int c2  = (sh * 32 + 4 * j) * 2;
      int off = swr + (c2 ^ swzs);
      *(unsigned long long*)(AsB + off) = pa.u;
      *(unsigned long long*)(BsB + off) = pb.u;
    }
    __syncthreads();
#pragma unroll
    for (int ks = 0; ks < 2; ++ks) {
      bf16x8 afr[4], bfr[4];
#pragma unroll
      for (int mi = 0; mi < 4; ++mi) {
        int row = wr * 64 + mi * 16 + (l & 15);
        int c2  = ks * 64 + (l >> 4) * 16;
        afr[mi] = *(const bf16x8*)(AsB + row * 128 + (c2 ^ ((row & 7) << 4)));
      }
#pragma unroll
      for (int ni = 0; ni < 4; ++ni) {
        int row = wc * 64 + ni * 16 + (l & 15);
        int c2  = ks * 64 + (l >> 4) * 16;
        bfr[ni] = *(const bf16x8*)(BsB + row * 128 + (c2 ^ ((row & 7) << 4)));
      }
#pragma unroll
      for (int mi = 0; mi < 4; ++mi)
#pragma unroll
        for (int ni = 0; ni < 4; ++ni)
          acc[mi][ni] = __builtin_amdgcn_mfma_f32_16x16x32_bf16(
              afr[mi], bfr[ni], acc[mi][ni], 0, 0, 0);
    }
    __syncthreads();
  }
  const int colb = bn * 128 + wc * 64 + (l & 15);
#pragma unroll
  for (int ni = 0; ni < 4; ++ni) {
    int col = colb + ni * 16;
    float bb = Bv[col];
#pragma unroll
    for (int mi = 0; mi < 4; ++mi) {
      int row = bm * 128 + wr * 64 + mi * 16 + ((l >> 4) << 2);
#pragma unroll
      for (int r = 0; r < 4; ++r)
        XP[(size_t)(row + r) * DIM + col] = acc[mi][ni][r] + bb;
    }
  }
}

// ---------------------------------------------------------------------------
// recurrence. waves_per_eu(4,4) grants a 128-VGPR budget; the asm pin on W4
// makes its defs non-rematerializable so the allocator MUST keep the 64-reg
// W slice resident (R8 proved it otherwise re-streams W from L2 every step:
// VGPR_Count stayed 64 and the 1.9us/step L2 floor remained).
// ---------------------------------------------------------------------------
__global__ __attribute__((amdgpu_flat_work_group_size(1024, 1024)))
__attribute__((amdgpu_waves_per_eu(4, 4)))
void rnn_kernel(const float* __restrict__ Wh, const float* __restrict__ Z,
                const float* __restrict__ gz, const float* __restrict__ gh,
                const float* __restrict__ bg,
                float* __restrict__ out,    // holds xp, overwritten with out
                float* __restrict__ hout,   // [T+1][B][D]
                u32x4* __restrict__ hX4) {
  __shared__ float hb[2][1024];
  const int tid = threadIdx.x;
  const int w   = tid >> 6;
  const int l   = tid & 63;
  const int b   = blockIdx.x >> 4;
  const int s   = blockIdx.x & 15;
  const int r0  = s * 64;
  const int myrow  = r0 + w * 4 + (l & 3);
  const bool writer = (l < 4);

  // W_h slice -> registers: wave w rows r0+4w..+3, lane l K-range [16l,16l+16)
  f32x4 W4[4][4];
  {
    const f32x4* WhV = (const f32x4*)Wh;
#pragma unroll
    for (int r4 = 0; r4 < 4; ++r4) {
      size_t base = (size_t)(r0 + w * 4 + r4) * (DIM / 4) + l * 4;
#pragma unroll
      for (int jj = 0; jj < 4; ++jj) W4[r4][jj] = WhV[base + jj];
    }
  }
  // PIN: make each W4 def an asm op -> not rematerializable -> stays in VGPRs.
#pragma unroll
  for (int r4 = 0; r4 < 4; ++r4)
#pragma unroll
    for (int jj = 0; jj < 4; ++jj)
      asm volatile("" : "+v"(W4[r4][jj]));

  float cgz = 0.f, cgh = 0.f, cbg = 0.f;
  float xpA = 0.f, zA = 0.f, xpB = 0.f, zB = 0.f;
  if (writer) {
    cgz = gz[myrow]; cgh = gh[myrow]; cbg = bg[myrow];
    xpA = out[(size_t)b * DIM + myrow];   // xp[0,b,myrow]
    zA  = Z[(size_t)b * DIM + myrow];
  }

#define TAGOK(Q) __all((int)((Q.x == tt) & (Q.w == tt)))
#define SCAT(K, Q, P) { int qi = 64 * K + l; int wi = ((qi ^ (qi >> 3)) & 255) << 2; \
    f32x4 v; v.x = __uint_as_float(Q.y << 16);                                       \
    v.y = __uint_as_float(Q.y & 0xFFFF0000u);                                        \
    v.z = __uint_as_float(Q.z << 16);                                                \
    v.w = __uint_as_float(Q.z & 0xFFFF0000u);                                        \
    *(f32x4*)&hb[P][wi] = v; }

#define STEP(P, XPC, ZC, XPN, ZN)                                                  \
  {                                                                                \
    const unsigned tt = (unsigned)t;                                               \
    const u32x4* srcq = hX4 + (size_t)(P) * SLOTS + (size_t)b * 256;               \
    u32x4*       dstq = hX4 + (size_t)(P ^ 1) * SLOTS + (size_t)b * 256;           \
    if (w == 0) {                                                                  \
      const char* ap = (const char*)srcq + (l << 4);                               \
      u32x4 q0, q1, q2, q3;                                                        \
      unsigned pend = 0xFu; int rounds = 0;                                        \
      do {                                                                         \
        if (pend & 1u) asm volatile("global_load_dwordx4 %0, %1, off sc1"          \
                                    : "=v"(q0) : "v"(ap) : "memory");              \
        if (pend & 2u) asm volatile("global_load_dwordx4 %0, %1, off offset:1024 sc1" \
                                    : "=v"(q1) : "v"(ap) : "memory");              \
        if (pend & 4u) asm volatile("global_load_dwordx4 %0, %1, off offset:2048 sc1" \
                                    : "=v"(q2) : "v"(ap) : "memory");              \
        if (pend & 8u) asm volatile("global_load_dwordx4 %0, %1, off offset:3072 sc1" \
                                    : "=v"(q3) : "v"(ap) : "memory");              \
        asm volatile("s_waitcnt vmcnt(0)" ::: "memory");                           \
        if ((pend & 1u) && TAGOK(q0)) { SCAT(0, q0, P); pend &= ~1u; }             \
        if ((pend & 2u) && TAGOK(q1)) { SCAT(1, q1, P); pend &= ~2u; }             \
        if ((pend & 4u) && TAGOK(q2)) { SCAT(2, q2, P); pend &= ~4u; }             \
        if ((pend & 8u) && TAGOK(q3)) { SCAT(3, q3, P); pend &= ~8u; }             \
      } while (pend && ++rounds < (1 << 22));                                      \
    }                                                                              \
    /* prefetch t+1 EARLY: ~1000cy before the next poll's vmcnt(0) drain */        \
    if (writer && t + 1 < T_STEPS) {                                               \
      XPN = out[((size_t)(t + 1) * BATCH + b) * DIM + myrow];                      \
      ZN  = Z[((size_t)(t + 1) * BATCH + b) * DIM + myrow];                        \
    }                                                                              \
    __syncthreads();                                                               \
    float acc0 = 0.f, acc1 = 0.f, acc2 = 0.f, acc3 = 0.f;                          \
    _Pragma("unroll")                                                              \
    for (int jj = 0; jj < 4; ++jj) {                                               \
      int qr = 4 * l + jj;                                                         \
      int wb = ((qr ^ (qr >> 3)) & 255) << 2;                                      \
      f32x4 h4 = *(const f32x4*)&hb[P][wb];                                        \
      _Pragma("unroll")                                                            \
      for (int i = 0; i < 4; ++i) {                                                \
        acc0 = fmaf(W4[0][jj][i], h4[i], acc0);                                    \
        acc1 = fmaf(W4[1][jj][i], h4[i], acc1);                                    \
        acc2 = fmaf(W4[2][jj][i], h4[i], acc2);                                    \
        acc3 = fmaf(W4[3][jj][i], h4[i], acc3);                                    \
      }                                                                            \
    }                                                                              \
    float w01 = (l & 1) ? acc0 : acc1;                                             \
    float v01 = ((l & 1) ? acc1 : acc0) + __shfl_xor(w01, 1);                      \
    float w23 = (l & 1) ? acc2 : acc3;                                             \
    float v23 = ((l & 1) ? acc3 : acc2) + __shfl_xor(w23, 1);                      \
    float wv  = (l & 2) ? v01 : v23;                                               \
    float vv  = ((l & 2) ? v23 : v01) + __shfl_xor(wv, 2);                         \
    vv += __shfl_xor(vv, 4);                                                       \
    vv += __shfl_xor(vv, 8);                                                       \
    vv += __shfl_xor(vv, 16);                                                      \
    vv += __shfl_xor(vv, 32);                                                      \
    if (writer) {                                                                  \
      float pre = vv + XPC;                                                        \
      float e2 = __expf(2.0f * pre);                                               \
      float hn = 1.0f - 2.0f / (e2 + 1.0f);                                        \
      float h1 = __shfl(hn, 1), h2 = __shfl(hn, 2), h3 = __shfl(hn, 3);            \
      if (l == 0) {                                                                \
        u32x4 pk;                                                                  \
        pk.x = tt + 1u; pk.w = tt + 1u;                                            \
        pk.y = bf16b(hn) | (bf16b(h1) << 16);                                      \
        pk.z = bf16b(h2) | (bf16b(h3) << 16);                                      \
        u32x4* pp = dstq + (s * 16 + w);                                           \
        asm volatile("global_store_dwordx4 %0, %1, off sc1"                        \
                     :: "v"(pp), "v"(pk) : "memory");                              \
      }                                                                            \
      hout[((size_t)(t + 1) * BATCH + b) * DIM + myrow] = hn;                      \
      float y   = ZC * cgz + hn * cgh + cbg;                                       \
      float sig = 1.0f / (1.0f + __expf(-y));                                      \
      out[((size_t)t * BATCH + b) * DIM + myrow] = hn * (y * sig);                 \
    }                                                                              \
  }

  for (int t = 0; t < T_STEPS; ) {
    STEP(0, xpA, zA, xpB, zB)
    ++t;
    STEP(1, xpB, zB, xpA, zA)
    ++t;
  }
#undef STEP
#undef SCAT
#undef TAGOK
}

extern "C" void kernel_launch(void* const* d_in, const int* in_sizes, int n_in,
                              void* d_out, int out_size, void* d_ws, size_t ws_size,
                              hipStream_t stream) {
  const float* x    = (const float*)d_in[0];
  const float* z    = (const float*)d_in[1];
  const float* h0   = (const float*)d_in[2];
  const float* Wx   = (const float*)d_in[3];
  const float* Wh   = (const float*)d_in[4];
  const float* bias = (const float*)d_in[5];
  const float* gz   = (const float*)d_in[6];
  const float* gh   = (const float*)d_in[7];
  const float* bg   = (const float*)d_in[8];

  float* out  = (float*)d_out;
  float* hout = out + (size_t)T_STEPS * BATCH * DIM;
  u32x4* hX4  = (u32x4*)d_ws;                        // 2*4096*16B = 128 KB

  prep_kernel<<<dim3(64), dim3(256), 0, stream>>>(h0, hout, hX4);
  xp_gemm<<<dim3(2048), dim3(256), 0, stream>>>(x, Wx, bias, out);
  rnn_kernel<<<dim3(256), dim3(1024), 0, stream>>>(Wh, z, gz, gh, bg, out, hout, hX4);
}